// Round 9
// baseline (719.598 us; speedup 1.0000x reference)
//
#include <hip/hip_runtime.h>
#include <math.h>

#define BLOCK_ 512
#define BPB_   8
#define NBLK_  (8192/BPB_)   // 1024 blocks

typedef __bf16 bf16x8 __attribute__((ext_vector_type(8)));
typedef float  f32x4  __attribute__((ext_vector_type(4)));
typedef unsigned short us8 __attribute__((ext_vector_type(8)));

// element strides (16B-aligned rows, <=2-way bank aliasing)
#define XS_  72    // x bf16      (144B)
#define QKS_ 136   // qk bf16     (272B)
#define VS_  72    // v bf16      (144B)
#define CS_  68    // canvas f32  (272B)
#define W1S_ 72
#define W2S_ 40
#define HGS_ 40    // H1g bf16 (overlays QK)

struct alignas(16) Smem {
    unsigned short Xb[81*XS_];    // 11664 B
    unsigned short QK[81*QKS_];   // 22032 B (q cols 0-63, k cols 64-127; H1g overlays)
    unsigned short Vf[81*VS_];    // 11664 B (bf16)
    float          Cv[81*CS_];    // 22032 B (atomic canvas)
    unsigned short W1[32*W1S_];   //  4608 B
    unsigned short W2[64*W2S_];   //  5120 B
    float Bias[81];
    float B1v[32], LnG[32], LnB[32], B2v[64];
};  // 78,084 B -> 2 blocks/CU by LDS

__device__ __forceinline__ unsigned short f2bf(float f) {
    union { float f; unsigned u; } v; v.f = f;
    unsigned r = v.u + 0x7FFFu + ((v.u >> 16) & 1u);   // RNE
    return (unsigned short)(r >> 16);
}
__device__ __forceinline__ float bf2f(unsigned short b) {
    union { float f; unsigned u; } v; v.u = ((unsigned)b) << 16;
    return v.f;
}
__device__ __forceinline__ us8 pack8(float4 a, float4 b) {
    us8 r;
    r[0]=f2bf(a.x); r[1]=f2bf(a.y); r[2]=f2bf(a.z); r[3]=f2bf(a.w);
    r[4]=f2bf(b.x); r[5]=f2bf(b.y); r[6]=f2bf(b.z); r[7]=f2bf(b.w);
    return r;
}
__device__ __forceinline__ us8 zero8() {
    us8 z;
    for (int e = 0; e < 8; ++e) z[e] = 0;
    return z;
}
__device__ __forceinline__ f32x4 zero4() {
    f32x4 z; z[0]=0.f; z[1]=0.f; z[2]=0.f; z[3]=0.f; return z;
}
__device__ __forceinline__ f32x4 mfma16(us8 a, us8 b, f32x4 c) {
    return __builtin_amdgcn_mfma_f32_16x16x32_bf16(
        __builtin_bit_cast(bf16x8, a), __builtin_bit_cast(bf16x8, b), c, 0, 0, 0);
}

__global__ __launch_bounds__(BLOCK_, 2)
void wattn_mfma(const float* __restrict__ x, const float* __restrict__ w_qkv,
                const float* __restrict__ pe, const float* __restrict__ w1,
                const float* __restrict__ b1, const float* __restrict__ lng,
                const float* __restrict__ lnb, const float* __restrict__ w2,
                const float* __restrict__ b2, float* __restrict__ out)
{
    __shared__ Smem sm;
    const int t = threadIdx.x;
    const int wv = t >> 6, lane = t & 63;
    const int lrow = lane & 15;          // li
    const int g    = lane >> 4;          // 16-lane group 0..3
    const int lk   = g * 8;              // A/B frag k-offset
    const int g4   = g * 4;              // D row-group
    const int ng = wv & 3, mg = wv >> 2;

    // ---------------- prologue: LDS weights + bias + zeros + x[0] ----------------
    for (int task = t; task < 32*8; task += BLOCK_) {
        int p = task >> 3, c8 = task & 7;
        const float4* src = (const float4*)(w1 + p*64 + c8*8);
        *(us8*)&sm.W1[p*W1S_ + c8*8] = pack8(src[0], src[1]);
    }
    for (int task = t; task < 64*4; task += BLOCK_) {
        int p = task >> 2, c8 = task & 3;
        const float4* src = (const float4*)(w2 + p*32 + c8*8);
        *(us8*)&sm.W2[p*W2S_ + c8*8] = pack8(src[0], src[1]);
    }
    if (t < 32) { sm.B1v[t]=b1[t]; sm.LnG[t]=lng[t]; sm.LnB[t]=lnb[t]; }
    if (t >= 64 && t < 128) sm.B2v[t-64] = b2[t-64];
    if (t >= 128 && t < 209) {
        int ij = t-128; int i = ij/9, j = ij%9;
        sm.Bias[ij] = pe[((j/3)-(i/3)+2)*5 + ((j%3)-(i%3)+2)];
    }
    for (int idx = t; idx < 81*CS_; idx += BLOCK_) sm.Cv[idx] = 0.f;
    {
        const float* xb = x + (size_t)blockIdx.x * BPB_ * (81*64);
        for (int task = t; task < 648; task += BLOCK_) {
            int p = task >> 3, c8 = task & 7;
            const float4* src = (const float4*)(xb + p*64 + c8*8);
            *(us8*)&sm.Xb[p*XS_ + c8*8] = pack8(src[0], src[1]);
        }
    }
    __syncthreads();

    for (int bi = 0; bi < BPB_; ++bi) {
        const size_t b = (size_t)blockIdx.x * BPB_ + bi;
        const bool hasPF = (bi + 1 < BPB_);
        const bool hasPF2 = hasPF && (t < 136);

        // -------- phase A: qkv = x @ Wqkv^T via MFMA (6m x 12n, K=64) --------
        {
            us8 af[3][2];
            #pragma unroll
            for (int mi = 0; mi < 3; ++mi) {
                const int arow = min(mg*48 + mi*16 + lrow, 80);
                #pragma unroll
                for (int k = 0; k < 2; ++k)
                    af[mi][k] = *(const us8*)&sm.Xb[arow*XS_ + k*32 + lk];
            }
            #pragma unroll
            for (int ni = 0; ni < 3; ++ni) {
                const int n = ng*3 + ni;
                us8 bq[2];
                #pragma unroll
                for (int k = 0; k < 2; ++k) {
                    const float4* src = (const float4*)(w_qkv + (n*16 + lrow)*64 + k*32 + lk);
                    bq[k] = pack8(src[0], src[1]);
                }
                f32x4 acc[3];
                #pragma unroll
                for (int mi = 0; mi < 3; ++mi) acc[mi] = zero4();
                #pragma unroll
                for (int k = 0; k < 2; ++k)
                    #pragma unroll
                    for (int mi = 0; mi < 3; ++mi)
                        acc[mi] = mfma16(af[mi][k], bq[k], acc[mi]);
                #pragma unroll
                for (int mi = 0; mi < 3; ++mi) {
                    const int row0 = mg*48 + mi*16 + g4;
                    if (n < 8) {
                        #pragma unroll
                        for (int r = 0; r < 4; ++r) {
                            int row = row0 + r;
                            if (row < 81) sm.QK[row*QKS_ + n*16 + lrow] = f2bf(acc[mi][r]);
                        }
                    } else {
                        #pragma unroll
                        for (int r = 0; r < 4; ++r) {
                            int row = row0 + r;
                            if (row < 81) sm.Vf[row*VS_ + (n-8)*16 + lrow] = f2bf(acc[mi][r]);
                        }
                    }
                }
            }
        }
        __syncthreads();

        // -------- phase C: MFMA attention, 64 (window,head) pairs, 8/wave --------
        // QK^T:  D[j][i] = sum_d K[j][d]*Q[i][d]  (A=K rows j=li, B=Q cols i=li, K-dim=d pad 32)
        // lane holds S[i=li][j=g*4+r]; softmax via 2x shfl_xor(16,32)
        // PV:    D2[i][d] = sum_j P[i][j]*V[j][d] (A=P rows i=li k=j, B=V cols d=li k=j)
        #pragma unroll
        for (int u = 0; u < 8; ++u) {
            const int pp = (wv << 3) | u;
            const int w = pp >> 2, h = pp & 3;
            const int base = (w >> 2) * 18 + (w & 3) * 2;   // r0*9 + c0
            const int cc  = min(lrow, 8);
            const int pos = base + (cc/3)*9 + (cc - (cc/3)*3);
            us8 aK = zero8(), bQ = zero8();
            if (g < 2) {
                aK = *(const us8*)&sm.QK[pos*QKS_ + 64 + h*16 + lk];
                bQ = *(const us8*)&sm.QK[pos*QKS_ + h*16 + lk];
            }
            f32x4 s4 = mfma16(aK, bQ, zero4());
            // softmax over j (16 j-slots spread across 4 groups; j>=9 masked)
            const int ib = cc * 9;
            float raw[4];
            #pragma unroll
            for (int r = 0; r < 4; ++r) {
                int j = g4 + r;
                raw[r] = (j < 9) ? s4[r]*0.25f + sm.Bias[ib + j] : -1e30f;
            }
            float mx = fmaxf(fmaxf(raw[0], raw[1]), fmaxf(raw[2], raw[3]));
            mx = fmaxf(mx, __shfl_xor(mx, 16));
            mx = fmaxf(mx, __shfl_xor(mx, 32));
            float ex[4]; float sum = 0.f;
            #pragma unroll
            for (int r = 0; r < 4; ++r) { ex[r] = __expf(raw[r] - mx); sum += ex[r]; }
            sum += __shfl_xor(sum, 16);
            sum += __shfl_xor(sum, 32);
            const float inv = 1.f / sum;
            float pf[4];
            #pragma unroll
            for (int r = 0; r < 4; ++r) pf[r] = ex[r] * inv;
            // route P into A-frag: g0 needs j0-7 (own + xor16), g1 needs j8 (xor48)
            float pg0 = __shfl_xor(pf[0], 16), pg1 = __shfl_xor(pf[1], 16);
            float pg2 = __shfl_xor(pf[2], 16), pg3 = __shfl_xor(pf[3], 16);
            float p8  = __shfl_xor(pf[0], 48);
            us8 a2 = zero8(), b2 = zero8();
            if (g == 0) {
                a2[0]=f2bf(pf[0]); a2[1]=f2bf(pf[1]); a2[2]=f2bf(pf[2]); a2[3]=f2bf(pf[3]);
                a2[4]=f2bf(pg0);  a2[5]=f2bf(pg1);  a2[6]=f2bf(pg2);  a2[7]=f2bf(pg3);
                const unsigned short* vb = &sm.Vf[base*VS_ + h*16 + lrow];
                b2[0]=vb[0];       b2[1]=vb[VS_];     b2[2]=vb[2*VS_];
                b2[3]=vb[9*VS_];   b2[4]=vb[10*VS_];  b2[5]=vb[11*VS_];
                b2[6]=vb[18*VS_];  b2[7]=vb[19*VS_];
            } else if (g == 1) {
                a2[0] = f2bf(p8);
                b2[0] = sm.Vf[(base+20)*VS_ + h*16 + lrow];
            }
            f32x4 o4 = mfma16(a2, b2, zero4());
            // scatter: O[i=g*4+r][d=lrow] -> canvas (idx576 = i*64+h*16+d)
            #pragma unroll
            for (int r = 0; r < 4; ++r) {
                int i = g4 + r;
                if (i < 9) {
                    int idx = i*64 + h*16 + lrow;
                    int c = idx/9, rr = idx - 9*c;
                    int row = base + (rr/3)*9 + (rr - (rr/3)*3);
                    atomicAdd(&sm.Cv[row*CS_ + c], o4[r]);
                }
            }
        }
        __syncthreads();

        // -------- issue next batch's x loads (held across G/J, written pre-final-barrier) --------
        float4 pA0, pA1, pB0, pB1;
        if (hasPF) {
            const float4* xn = (const float4*)(x + (b+1)*(81*64));
            pA0 = xn[t*2]; pA1 = xn[t*2+1];
            if (hasPF2) { pB0 = xn[(512+t)*2]; pB1 = xn[(512+t)*2+1]; }
        }

        // -------- phase G: MLP1 MFMA + in-reg LN + gelu --------
        if (wv < 6) {
            const int m = wv;
            const int arow = m*16 + lrow;
            us8 aF[2];
            #pragma unroll
            for (int k = 0; k < 2; ++k) {
                aF[k] = zero8();
                if (arow < 81) {
                    const float* cp = &sm.Cv[arow*CS_ + k*32 + lk];
                    aF[k] = pack8(*(const float4*)cp, *(const float4*)(cp+4));
                }
            }
            f32x4 a0 = zero4(), a1 = zero4();
            #pragma unroll
            for (int k = 0; k < 2; ++k) {
                us8 b0  = *(const us8*)&sm.W1[lrow*W1S_ + k*32 + lk];
                us8 b1f = *(const us8*)&sm.W1[(16+lrow)*W1S_ + k*32 + lk];
                a0 = mfma16(aF[k], b0, a0);
                a1 = mfma16(aF[k], b1f, a1);
            }
            float bb0 = sm.B1v[lrow], bb1 = sm.B1v[16+lrow];
            float gg0 = sm.LnG[lrow], gg1 = sm.LnG[16+lrow];
            float ee0 = sm.LnB[lrow], ee1 = sm.LnB[16+lrow];
            float v0[4], v1[4], srow[4], qrow[4];
            #pragma unroll
            for (int r=0;r<4;++r) {
                v0[r] = a0[r] + bb0; v1[r] = a1[r] + bb1;
                srow[r] = v0[r] + v1[r];
                qrow[r] = v0[r]*v0[r] + v1[r]*v1[r];
            }
            #pragma unroll
            for (int mask = 1; mask <= 8; mask <<= 1)
                #pragma unroll
                for (int r=0;r<4;++r) {
                    srow[r] += __shfl_xor(srow[r], mask);
                    qrow[r] += __shfl_xor(qrow[r], mask);
                }
            unsigned short* H1g = sm.QK;   // overlays dead QK
            #pragma unroll
            for (int r=0;r<4;++r) {
                int row = m*16 + g4 + r;
                if (row < 81) {
                    float mean = srow[r]*(1.f/32.f);
                    float var  = qrow[r]*(1.f/32.f) - mean*mean;
                    float rs   = rsqrtf(var + 1e-5f);
                    float xn0 = (v0[r]-mean)*rs*gg0 + ee0;
                    float xn1 = (v1[r]-mean)*rs*gg1 + ee1;
                    float ge0 = 0.5f*xn0*(1.f + erff(xn0*0.70710678118654752f));
                    float ge1 = 0.5f*xn1*(1.f + erff(xn1*0.70710678118654752f));
                    H1g[row*HGS_ + lrow]      = f2bf(ge0);
                    H1g[row*HGS_ + 16 + lrow] = f2bf(ge1);
                }
            }
        }
        __syncthreads();

        // -------- phase J: MLP2 MFMA -> global; write prefetch; re-zero canvas --------
        {
            const unsigned short* H1g = sm.QK;
            #pragma unroll
            for (int ti = 0; ti < 3; ++ti) {
                int ft = wv*3 + ti;
                int m = ft >> 2, n = ft & 3;
                int arow = m*16 + lrow;
                us8 aH = zero8();
                if (arow < 81) aH = *(const us8*)&H1g[arow*HGS_ + lk];
                us8 bW = *(const us8*)&sm.W2[(n*16+lrow)*W2S_ + lk];
                f32x4 acc = mfma16(aH, bW, zero4());
                float bb = sm.B2v[n*16+lrow];
                int row0 = m*16 + g4;
                #pragma unroll
                for (int r=0;r<4;++r) {
                    int row = row0 + r;
                    if (row < 81)
                        out[(b*81 + (size_t)row)*64 + n*16 + lrow] = acc[r] + bb;
                }
            }
        }
        if (hasPF) {
            int p = t >> 3, c8 = t & 7;
            *(us8*)&sm.Xb[p*XS_ + c8*8] = pack8(pA0, pA1);
            if (hasPF2) {
                int task = 512 + t; p = task >> 3; c8 = task & 7;
                *(us8*)&sm.Xb[p*XS_ + c8*8] = pack8(pB0, pB1);
            }
        }
        for (int idx = t; idx < 81*CS_; idx += BLOCK_) sm.Cv[idx] = 0.f;
        __syncthreads();
    }
}

extern "C" void kernel_launch(void* const* d_in, const int* in_sizes, int n_in,
                              void* d_out, int out_size, void* d_ws, size_t ws_size,
                              hipStream_t stream) {
    const float* x     = (const float*)d_in[0];
    const float* w_qkv = (const float*)d_in[1];
    const float* pe    = (const float*)d_in[2];
    const float* w1    = (const float*)d_in[3];
    const float* b1    = (const float*)d_in[4];
    const float* lng   = (const float*)d_in[5];
    const float* lnb   = (const float*)d_in[6];
    const float* w2    = (const float*)d_in[7];
    const float* b2    = (const float*)d_in[8];
    float* outp = (float*)d_out;

    wattn_mfma<<<dim3(NBLK_), dim3(BLOCK_), 0, stream>>>(
        x, w_qkv, pe, w1, b1, lng, lnb, w2, b2, outp);
}

// Round 10
// 705.345 us; speedup vs baseline: 1.0202x; 1.0202x over previous
//
#include <hip/hip_runtime.h>
#include <math.h>

#define BLOCK_ 512
#define BPB_   8
#define NBLK_  (8192/BPB_)   // 1024 blocks (K1)
#define K2B_   256
#define K2NBLK_ (8192/4)     // 2048 blocks (K2), 4 waves = 4 batches each

typedef __bf16 bf16x8 __attribute__((ext_vector_type(8)));
typedef float  f32x4  __attribute__((ext_vector_type(4)));
typedef unsigned short us8 __attribute__((ext_vector_type(8)));

// element strides
#define XS_  72    // x bf16       (144B rows, 16B-aligned)
#define QKS_ 136   // qk bf16      (272B)
#define VSK_ 68    // v bf16       (136B; scalar access only)
#define CS_  68    // canvas f32   (272B)
#define W1S_ 72
#define W2S_ 40
#define HGS_ 40    // H1g bf16

struct alignas(16) SmemK1 {
    unsigned short Xb[81*XS_];    // 11664 B
    unsigned short QK[81*QKS_];   // 22032 B (q cols 0-63, k cols 64-127)
    unsigned short Vf[81*VSK_];   // 11016 B
    float          Cv[81*CS_];    // 22032 B (atomic canvas)
    float Bias[81];
};  // 67,068 B -> 2 blocks/CU by LDS

struct alignas(16) SmemK2 {
    unsigned short W1[32*W1S_];     // 4608 B
    unsigned short W2[64*W2S_];     // 5120 B
    unsigned short H1g[4][81*HGS_]; // 25920 B (per-wave slices)
    float B1v[32], LnG[32], LnB[32], B2v[64];
};  // 36,288 B -> 4 blocks/CU

__device__ __forceinline__ unsigned short f2bf(float f) {
    union { float f; unsigned u; } v; v.f = f;
    unsigned r = v.u + 0x7FFFu + ((v.u >> 16) & 1u);   // RNE
    return (unsigned short)(r >> 16);
}
__device__ __forceinline__ us8 pack8(float4 a, float4 b) {
    us8 r;
    r[0]=f2bf(a.x); r[1]=f2bf(a.y); r[2]=f2bf(a.z); r[3]=f2bf(a.w);
    r[4]=f2bf(b.x); r[5]=f2bf(b.y); r[6]=f2bf(b.z); r[7]=f2bf(b.w);
    return r;
}
__device__ __forceinline__ us8 zero8() {
    us8 z;
    for (int e = 0; e < 8; ++e) z[e] = 0;
    return z;
}
__device__ __forceinline__ f32x4 zero4() {
    f32x4 z; z[0]=0.f; z[1]=0.f; z[2]=0.f; z[3]=0.f; return z;
}
__device__ __forceinline__ f32x4 mfma16(us8 a, us8 b, f32x4 c) {
    return __builtin_amdgcn_mfma_f32_16x16x32_bf16(
        __builtin_bit_cast(bf16x8, a), __builtin_bit_cast(bf16x8, b), c, 0, 0, 0);
}

// ================= K1: qkv GEMM + MFMA attention + scatter -> canvas ==========
__global__ __launch_bounds__(BLOCK_, 2)
void wattn_k1(const float* __restrict__ x, const float* __restrict__ w_qkv,
              const float* __restrict__ pe, float* __restrict__ canvas)
{
    __shared__ SmemK1 sm;
    const int t = threadIdx.x;
    const int wv = t >> 6, lane = t & 63;
    const int lrow = lane & 15;
    const int g    = lane >> 4;
    const int lk   = g * 8;
    const int g4   = g * 4;
    const int ng = wv & 3, mg = wv >> 2;

    // ---- prologue: bias + x[0] ----
    if (t >= 128 && t < 209) {
        int ij = t-128; int i = ij/9, j = ij%9;
        sm.Bias[ij] = pe[((j/3)-(i/3)+2)*5 + ((j%3)-(i%3)+2)];
    }
    {
        const float* xb = x + (size_t)blockIdx.x * BPB_ * (81*64);
        for (int task = t; task < 648; task += BLOCK_) {
            int p = task >> 3, c8 = task & 7;
            const float4* src = (const float4*)(xb + p*64 + c8*8);
            *(us8*)&sm.Xb[p*XS_ + c8*8] = pack8(src[0], src[1]);
        }
    }
    __syncthreads();

    for (int bi = 0; bi < BPB_; ++bi) {
        const size_t b = (size_t)blockIdx.x * BPB_ + bi;
        const bool hasPF = (bi + 1 < BPB_);
        const bool hasPF2 = hasPF && (t < 136);

        // -------- phase A: qkv = x @ Wqkv^T (6m x 12n, K=64) + zero canvas --------
        {
            us8 af[3][2];
            #pragma unroll
            for (int mi = 0; mi < 3; ++mi) {
                const int arow = min(mg*48 + mi*16 + lrow, 80);
                #pragma unroll
                for (int k = 0; k < 2; ++k)
                    af[mi][k] = *(const us8*)&sm.Xb[arow*XS_ + k*32 + lk];
            }
            #pragma unroll
            for (int ni = 0; ni < 3; ++ni) {
                const int n = ng*3 + ni;
                us8 bq[2];
                #pragma unroll
                for (int k = 0; k < 2; ++k) {
                    const float4* src = (const float4*)(w_qkv + (n*16 + lrow)*64 + k*32 + lk);
                    bq[k] = pack8(src[0], src[1]);
                }
                f32x4 acc[3];
                #pragma unroll
                for (int mi = 0; mi < 3; ++mi) acc[mi] = zero4();
                #pragma unroll
                for (int k = 0; k < 2; ++k)
                    #pragma unroll
                    for (int mi = 0; mi < 3; ++mi)
                        acc[mi] = mfma16(af[mi][k], bq[k], acc[mi]);
                #pragma unroll
                for (int mi = 0; mi < 3; ++mi) {
                    const int row0 = mg*48 + mi*16 + g4;
                    if (n < 8) {
                        #pragma unroll
                        for (int r = 0; r < 4; ++r) {
                            int row = row0 + r;
                            if (row < 81) sm.QK[row*QKS_ + n*16 + lrow] = f2bf(acc[mi][r]);
                        }
                    } else {
                        #pragma unroll
                        for (int r = 0; r < 4; ++r) {
                            int row = row0 + r;
                            if (row < 81) sm.Vf[row*VSK_ + (n-8)*16 + lrow] = f2bf(acc[mi][r]);
                        }
                    }
                }
            }
        }
        for (int idx = t; idx < 81*CS_; idx += BLOCK_) sm.Cv[idx] = 0.f;
        __syncthreads();

        // -------- phase C: MFMA attention, 64 (window,head) pairs, 8/wave --------
        #pragma unroll
        for (int u = 0; u < 8; ++u) {
            const int pp = (wv << 3) | u;
            const int w = pp >> 2, h = pp & 3;
            const int base = (w >> 2) * 18 + (w & 3) * 2;   // r0*9 + c0
            const int cc  = min(lrow, 8);
            const int pos = base + (cc/3)*9 + (cc - (cc/3)*3);
            us8 aK = zero8(), bQ = zero8();
            if (g < 2) {
                aK = *(const us8*)&sm.QK[pos*QKS_ + 64 + h*16 + lk];
                bQ = *(const us8*)&sm.QK[pos*QKS_ + h*16 + lk];
            }
            f32x4 s4 = mfma16(aK, bQ, zero4());
            const int ib = cc * 9;
            float raw[4];
            #pragma unroll
            for (int r = 0; r < 4; ++r) {
                int j = g4 + r;
                raw[r] = (j < 9) ? s4[r]*0.25f + sm.Bias[ib + j] : -1e30f;
            }
            float mx = fmaxf(fmaxf(raw[0], raw[1]), fmaxf(raw[2], raw[3]));
            mx = fmaxf(mx, __shfl_xor(mx, 16));
            mx = fmaxf(mx, __shfl_xor(mx, 32));
            float ex[4]; float sum = 0.f;
            #pragma unroll
            for (int r = 0; r < 4; ++r) { ex[r] = __expf(raw[r] - mx); sum += ex[r]; }
            sum += __shfl_xor(sum, 16);
            sum += __shfl_xor(sum, 32);
            const float inv = 1.f / sum;
            float pf[4];
            #pragma unroll
            for (int r = 0; r < 4; ++r) pf[r] = ex[r] * inv;
            float pg0 = __shfl_xor(pf[0], 16), pg1 = __shfl_xor(pf[1], 16);
            float pg2 = __shfl_xor(pf[2], 16), pg3 = __shfl_xor(pf[3], 16);
            float p8  = __shfl_xor(pf[0], 48);
            us8 a2 = zero8(), b2 = zero8();
            if (g == 0) {
                a2[0]=f2bf(pf[0]); a2[1]=f2bf(pf[1]); a2[2]=f2bf(pf[2]); a2[3]=f2bf(pf[3]);
                a2[4]=f2bf(pg0);  a2[5]=f2bf(pg1);  a2[6]=f2bf(pg2);  a2[7]=f2bf(pg3);
                const unsigned short* vb = &sm.Vf[base*VSK_ + h*16 + lrow];
                b2[0]=vb[0];        b2[1]=vb[VSK_];     b2[2]=vb[2*VSK_];
                b2[3]=vb[9*VSK_];   b2[4]=vb[10*VSK_];  b2[5]=vb[11*VSK_];
                b2[6]=vb[18*VSK_];  b2[7]=vb[19*VSK_];
            } else if (g == 1) {
                a2[0] = f2bf(p8);
                b2[0] = sm.Vf[(base+20)*VSK_ + h*16 + lrow];
            }
            f32x4 o4 = mfma16(a2, b2, zero4());
            #pragma unroll
            for (int r = 0; r < 4; ++r) {
                int i = g4 + r;
                if (i < 9) {
                    int idx = i*64 + h*16 + lrow;
                    int c = idx/9, rr = idx - 9*c;
                    int row = base + (rr/3)*9 + (rr - (rr/3)*3);
                    atomicAdd(&sm.Cv[row*CS_ + c], o4[r]);
                }
            }
        }
        __syncthreads();

        // -------- phase S: canvas -> global; prefetch next x into Xb --------
        float4 pA0, pA1, pB0, pB1;
        if (hasPF) {
            const float4* xn = (const float4*)(x + (b+1)*(81*64));
            pA0 = xn[t*2]; pA1 = xn[t*2+1];
            if (hasPF2) { pB0 = xn[(512+t)*2]; pB1 = xn[(512+t)*2+1]; }
        }
        for (int idx = t; idx < 81*16; idx += BLOCK_) {
            int p = idx >> 4, c4 = idx & 15;
            *(float4*)&canvas[(b*81 + (size_t)p)*64 + c4*4] =
                *(const float4*)&sm.Cv[p*CS_ + c4*4];
        }
        if (hasPF) {
            int p = t >> 3, c8 = t & 7;
            *(us8*)&sm.Xb[p*XS_ + c8*8] = pack8(pA0, pA1);
            if (hasPF2) {
                int task = 512 + t; p = task >> 3; c8 = task & 7;
                *(us8*)&sm.Xb[p*XS_ + c8*8] = pack8(pB0, pB1);
            }
        }
        __syncthreads();
    }
}

// ================= K2: MLP over canvas, in-place on out ==========
// 256 threads = 4 waves, each wave owns one batch; no inter-wave deps after
// the weight-staging barrier. Reads canvas rows (global), overwrites same rows.
__global__ __launch_bounds__(K2B_, 4)
void wattn_k2(float* __restrict__ io, const float* __restrict__ w1,
              const float* __restrict__ b1, const float* __restrict__ lng,
              const float* __restrict__ lnb, const float* __restrict__ w2,
              const float* __restrict__ b2)
{
    __shared__ SmemK2 sm;
    const int t = threadIdx.x;
    const int wv = t >> 6, lane = t & 63;
    const int lrow = lane & 15;
    const int g    = lane >> 4;
    const int lk   = g * 8;
    const int g4   = g * 4;

    // ---- stage weights ----
    for (int task = t; task < 32*8; task += K2B_) {
        int p = task >> 3, c8 = task & 7;
        const float4* src = (const float4*)(w1 + p*64 + c8*8);
        *(us8*)&sm.W1[p*W1S_ + c8*8] = pack8(src[0], src[1]);
    }
    for (int task = t; task < 64*4; task += K2B_) {
        int p = task >> 2, c8 = task & 3;
        const float4* src = (const float4*)(w2 + p*32 + c8*8);
        *(us8*)&sm.W2[p*W2S_ + c8*8] = pack8(src[0], src[1]);
    }
    if (t < 32) { sm.B1v[t]=b1[t]; sm.LnG[t]=lng[t]; sm.LnB[t]=lnb[t]; }
    if (t >= 64 && t < 128) sm.B2v[t-64] = b2[t-64];
    __syncthreads();

    const size_t b = (size_t)blockIdx.x * 4 + wv;
    float* canv = io + b * (81*64);
    unsigned short* H1g = sm.H1g[wv];

    const float bb0 = sm.B1v[lrow], bb1 = sm.B1v[16+lrow];
    const float gg0 = sm.LnG[lrow], gg1 = sm.LnG[16+lrow];
    const float ee0 = sm.LnB[lrow], ee1 = sm.LnB[16+lrow];

    #pragma unroll
    for (int m = 0; m < 6; ++m) {
        // ---- MLP1: canvas rows (global) -> h1 ----
        const int arow = m*16 + lrow;
        us8 aF[2];
        #pragma unroll
        for (int k = 0; k < 2; ++k) {
            aF[k] = zero8();
            if (arow < 81) {
                const float* cp = canv + arow*64 + k*32 + lk;
                aF[k] = pack8(*(const float4*)cp, *(const float4*)(cp+4));
            }
        }
        f32x4 a0 = zero4(), a1 = zero4();
        #pragma unroll
        for (int k = 0; k < 2; ++k) {
            us8 b0  = *(const us8*)&sm.W1[lrow*W1S_ + k*32 + lk];
            us8 b1f = *(const us8*)&sm.W1[(16+lrow)*W1S_ + k*32 + lk];
            a0 = mfma16(aF[k], b0, a0);
            a1 = mfma16(aF[k], b1f, a1);
        }
        // ---- LN + gelu -> H1g (per-wave LDS slice) ----
        float v0[4], v1[4], srow[4], qrow[4];
        #pragma unroll
        for (int r=0;r<4;++r) {
            v0[r] = a0[r] + bb0; v1[r] = a1[r] + bb1;
            srow[r] = v0[r] + v1[r];
            qrow[r] = v0[r]*v0[r] + v1[r]*v1[r];
        }
        #pragma unroll
        for (int mask = 1; mask <= 8; mask <<= 1)
            #pragma unroll
            for (int r=0;r<4;++r) {
                srow[r] += __shfl_xor(srow[r], mask);
                qrow[r] += __shfl_xor(qrow[r], mask);
            }
        #pragma unroll
        for (int r=0;r<4;++r) {
            int row = m*16 + g4 + r;
            if (row < 81) {
                float mean = srow[r]*(1.f/32.f);
                float var  = qrow[r]*(1.f/32.f) - mean*mean;
                float rs   = rsqrtf(var + 1e-5f);
                float xn0 = (v0[r]-mean)*rs*gg0 + ee0;
                float xn1 = (v1[r]-mean)*rs*gg1 + ee1;
                float ge0 = 0.5f*xn0*(1.f + erff(xn0*0.70710678118654752f));
                float ge1 = 0.5f*xn1*(1.f + erff(xn1*0.70710678118654752f));
                H1g[row*HGS_ + lrow]      = f2bf(ge0);
                H1g[row*HGS_ + 16 + lrow] = f2bf(ge1);
            }
        }
        // ---- MLP2: H1g -> out (overwrites this m-tile's canvas rows) ----
        us8 aH = zero8();
        if (arow < 81) aH = *(const us8*)&H1g[arow*HGS_ + lk];
        #pragma unroll
        for (int n = 0; n < 4; ++n) {
            us8 bW = *(const us8*)&sm.W2[(n*16+lrow)*W2S_ + lk];
            f32x4 acc = mfma16(aH, bW, zero4());
            float bb = sm.B2v[n*16+lrow];
            #pragma unroll
            for (int r=0;r<4;++r) {
                int row = m*16 + g4 + r;
                if (row < 81)
                    canv[row*64 + n*16 + lrow] = acc[r] + bb;
            }
        }
    }
}

extern "C" void kernel_launch(void* const* d_in, const int* in_sizes, int n_in,
                              void* d_out, int out_size, void* d_ws, size_t ws_size,
                              hipStream_t stream) {
    const float* x     = (const float*)d_in[0];
    const float* w_qkv = (const float*)d_in[1];
    const float* pe    = (const float*)d_in[2];
    const float* w1    = (const float*)d_in[3];
    const float* b1    = (const float*)d_in[4];
    const float* lng   = (const float*)d_in[5];
    const float* lnb   = (const float*)d_in[6];
    const float* w2    = (const float*)d_in[7];
    const float* b2    = (const float*)d_in[8];
    float* outp = (float*)d_out;

    wattn_k1<<<dim3(NBLK_), dim3(BLOCK_), 0, stream>>>(x, w_qkv, pe, outp);
    wattn_k2<<<dim3(K2NBLK_), dim3(K2B_), 0, stream>>>(outp, w1, b1, lng, lnb, w2, b2);
}